// Round 16
// baseline (122.435 us; speedup 1.0000x reference)
//
#include <hip/hip_runtime.h>
#include <hip/hip_fp16.h>
#include <math.h>

#ifndef __has_builtin
#define __has_builtin(x) 0
#endif

#define N_NODES 10000
#define N_EDGES 320000
#define ET (N_EDGES + N_NODES)        // edges + self-loops
#define CAP 128                       // per-node CSR bucket capacity (max deg ~60)
#define NB_G1 (157 * 5)               // gemm1 blocks in fused launch
#define NB_SCT ((ET + 255) / 256)     // scatter blocks in fused launch

// k_init region sizes
#define IB_CUR 40                     // cursor zero
#define IB_X   1250                   // x -> fp16 (320K float4)
#define IB_W1  160                    // W1 -> fp16 transposed (40960 elems)
#define IB_W2  80                     // W2 -> fp16 transposed (20480 elems)
#define NB_INIT (IB_CUR + IB_X + IB_W1 + IB_W2)

typedef _Float16 f16x2 __attribute__((ext_vector_type(2)));

__device__ __forceinline__ float dot2f(unsigned xu, unsigned wu, float acc) {
  f16x2 xv = *reinterpret_cast<const f16x2*>(&xu);
  f16x2 wv = *reinterpret_cast<const f16x2*>(&wu);
#if __has_builtin(__builtin_amdgcn_fdot2)
  return __builtin_amdgcn_fdot2(xv, wv, acc, false);
#else
  return acc + (float)xv.x * (float)wv.x + (float)xv.y * (float)wv.y;
#endif
}

__device__ __forceinline__ float dot8(uint4 x, uint4 w, float acc) {
  acc = dot2f(x.x, w.x, acc);
  acc = dot2f(x.y, w.y, acc);
  acc = dot2f(x.z, w.z, acc);
  acc = dot2f(x.w, w.w, acc);
  return acc;
}

__device__ __forceinline__ float lrelu_exp(float e) {
  e = (e > 0.f) ? e : 0.2f * e;   // leaky_relu
  return __expf(e);               // logits O(+-6): no max-shift needed
}

__device__ __forceinline__ void ld_half8(const __half* p, float4& lo, float4& hi) {
  uint4 u = *reinterpret_cast<const uint4*>(p);
  float2 f0 = __half22float2(*reinterpret_cast<const __half2*>(&u.x));
  float2 f1 = __half22float2(*reinterpret_cast<const __half2*>(&u.y));
  float2 f2 = __half22float2(*reinterpret_cast<const __half2*>(&u.z));
  float2 f3 = __half22float2(*reinterpret_cast<const __half2*>(&u.w));
  lo = make_float4(f0.x, f0.y, f1.x, f1.y);
  hi = make_float4(f2.x, f2.y, f3.x, f3.y);
}

__device__ __forceinline__ void st_half4(__half* p, float4 v) {
  __half2 lo = __float22half2_rn(make_float2(v.x, v.y));
  __half2 hi = __float22half2_rn(make_float2(v.z, v.w));
  uint2 u;
  u.x = *reinterpret_cast<const unsigned*>(&lo);
  u.y = *reinterpret_cast<const unsigned*>(&hi);
  *reinterpret_cast<uint2*>(p) = u;
}

__device__ __forceinline__ void st_half8(__half* p, float4 lo, float4 hi) {
  __half2 q0 = __float22half2_rn(make_float2(lo.x, lo.y));
  __half2 q1 = __float22half2_rn(make_float2(lo.z, lo.w));
  __half2 q2 = __float22half2_rn(make_float2(hi.x, hi.y));
  __half2 q3 = __float22half2_rn(make_float2(hi.z, hi.w));
  uint4 u;
  u.x = *reinterpret_cast<const unsigned*>(&q0);
  u.y = *reinterpret_cast<const unsigned*>(&q1);
  u.z = *reinterpret_cast<const unsigned*>(&q2);
  u.w = *reinterpret_cast<const unsigned*>(&q3);
  *reinterpret_cast<uint4*>(p) = u;
}

// ---- init: zero cursor + fp16 conversions (x, W1 transposed, W2 transposed) ----

__global__ __launch_bounds__(256) void k_init(int* __restrict__ cursor,
                                              const float* __restrict__ x, __half* __restrict__ xh,
                                              const float* __restrict__ W1, __half* __restrict__ W1t,
                                              const float* __restrict__ W2, __half* __restrict__ W2t) {
  int bid = blockIdx.x, t = threadIdx.x;
  if (bid < IB_CUR) {
    int i = bid * 256 + t;
    if (i < N_NODES) cursor[i] = 0;
  } else if (bid < IB_CUR + IB_X) {
    int idx = (bid - IB_CUR) * 256 + t;          // float4 chunk id, 320000 total
    if (idx < N_NODES * 32) {
      float4 v = *reinterpret_cast<const float4*>(&x[(size_t)idx * 4]);
      st_half4(&xh[(size_t)idx * 4], v);
    }
  } else if (bid < IB_CUR + IB_X + IB_W1) {
    int idx = (bid - IB_CUR - IB_X) * 256 + t;   // 128*320 = 40960
    if (idx < 128 * 320) {
      int k = idx / 320, c = idx % 320;
      W1t[(size_t)c * 128 + k] = __float2half_rn(W1[idx]);
    }
  } else {
    int idx = (bid - IB_CUR - IB_X - IB_W1) * 256 + t;  // 320*64 = 20480
    if (idx < 320 * 64) {
      int k = idx / 64, c = idx % 64;
      W2t[(size_t)c * 320 + k] = __float2half_rn(W2[idx]);
    }
  }
}

// ------- fused: gemm1 via fdot2 (blocks 0..784, h1 fp16) + bucket-scatter -------

__global__ __launch_bounds__(256) void k_gemm1_scatter(const __half* __restrict__ xh, const __half* __restrict__ W1t,
                                                       const float* __restrict__ att_src, const float* __restrict__ att_dst,
                                                       __half* __restrict__ h1, float* __restrict__ a_src,
                                                       float* __restrict__ a_dst,
                                                       const int* __restrict__ ei, int* __restrict__ cursor,
                                                       int* __restrict__ csr) {
  __shared__ __half xs_h[64][136];     // row stride 272B (17x16B): aligned, low-conflict
  int bid = blockIdx.x;
  int t = threadIdx.x;
  if (bid >= NB_G1) {                  // ---- scatter path ----
    int i = (bid - NB_G1) * 256 + t;
    if (i < ET) {
      int src, dst;
      if (i < N_EDGES) { src = ei[i]; dst = ei[N_EDGES + i]; }
      else             { src = dst = i - N_EDGES; }
      int pos = (dst << 7) + atomicAdd(&cursor[dst], 1);
      csr[pos] = src;
    }
    return;
  }
  // ---- gemm1: 64-row x 64-col tile, head = bid/157, fp16 inputs, fdot2 ----
  int h = bid / 157;
  int rb = (bid % 157) * 64;
#pragma unroll
  for (int i = 0; i < 4; ++i) {
    int idx = t + 256 * i;             // 1024 chunks: 64 rows x 16 k-octets
    int row = idx >> 4, ko = idx & 15;
    int gr = rb + row;
    uint4 v = make_uint4(0, 0, 0, 0);
    if (gr < N_NODES) v = *reinterpret_cast<const uint4*>(&xh[(size_t)gr * 128 + ko * 8]);
    *reinterpret_cast<uint4*>(&xs_h[row][ko * 8]) = v;
  }
  __syncthreads();
  int cg = t & 15, rg = t >> 4;
  int c0 = cg * 4, r0 = rg * 4;
  const __half* __restrict__ wt = W1t + (size_t)(h * 64 + c0) * 128;
  float4 a0 = make_float4(0.f, 0.f, 0.f, 0.f), a1 = a0, a2 = a0, a3 = a0;
#pragma unroll 4
  for (int ko = 0; ko < 16; ++ko) {
    uint4 x0 = *reinterpret_cast<const uint4*>(&xs_h[r0 + 0][ko * 8]);
    uint4 x1 = *reinterpret_cast<const uint4*>(&xs_h[r0 + 1][ko * 8]);
    uint4 x2 = *reinterpret_cast<const uint4*>(&xs_h[r0 + 2][ko * 8]);
    uint4 x3 = *reinterpret_cast<const uint4*>(&xs_h[r0 + 3][ko * 8]);
    uint4 w0 = *reinterpret_cast<const uint4*>(wt + 0 * 128 + ko * 8);
    uint4 w1 = *reinterpret_cast<const uint4*>(wt + 1 * 128 + ko * 8);
    uint4 w2 = *reinterpret_cast<const uint4*>(wt + 2 * 128 + ko * 8);
    uint4 w3 = *reinterpret_cast<const uint4*>(wt + 3 * 128 + ko * 8);
    a0.x = dot8(x0, w0, a0.x); a0.y = dot8(x0, w1, a0.y); a0.z = dot8(x0, w2, a0.z); a0.w = dot8(x0, w3, a0.w);
    a1.x = dot8(x1, w0, a1.x); a1.y = dot8(x1, w1, a1.y); a1.z = dot8(x1, w2, a1.z); a1.w = dot8(x1, w3, a1.w);
    a2.x = dot8(x2, w0, a2.x); a2.y = dot8(x2, w1, a2.y); a2.z = dot8(x2, w2, a2.z); a2.w = dot8(x2, w3, a2.w);
    a3.x = dot8(x3, w0, a3.x); a3.y = dot8(x3, w1, a3.y); a3.z = dot8(x3, w2, a3.z); a3.w = dot8(x3, w3, a3.w);
  }
  float4 asv = *reinterpret_cast<const float4*>(&att_src[h * 64 + c0]);
  float4 adv = *reinterpret_cast<const float4*>(&att_dst[h * 64 + c0]);
#pragma unroll
  for (int rr = 0; rr < 4; ++rr) {
    float4 ar = (rr == 0) ? a0 : (rr == 1) ? a1 : (rr == 2) ? a2 : a3;
    float vs = ar.x * asv.x + ar.y * asv.y + ar.z * asv.z + ar.w * asv.w;
    float vd = ar.x * adv.x + ar.y * adv.y + ar.z * adv.z + ar.w * adv.w;
#pragma unroll
    for (int m = 1; m < 16; m <<= 1) { vs += __shfl_xor(vs, m); vd += __shfl_xor(vd, m); }
    int gr = rb + r0 + rr;
    if (gr < N_NODES) {
      if (cg == 0) { a_src[h * N_NODES + gr] = vs; a_dst[h * N_NODES + gr] = vd; }
      st_half4(&h1[(size_t)gr * 320 + h * 64 + c0], ar);
    }
  }
}

// ---- agg1: 8 edge-slots x 8 lanes/edge, 16B fp16 gathers; out1 in fp16 ----

__global__ __launch_bounds__(256) void k_agg1(const __half* __restrict__ h1, const float* __restrict__ a_src,
                                              const float* __restrict__ a_dst, const float* __restrict__ b1,
                                              const int* __restrict__ degs, const int* __restrict__ csr,
                                              __half* __restrict__ out1h) {
  int lane = threadIdx.x & 63, wid = threadIdx.x >> 6;
  int n = blockIdx.x * 4 + wid;
  int h = blockIdx.y;
  int sub = lane >> 3;        // edge slot 0..7
  int cg = lane & 7;          // channel octet
  int beg = n << 7;
  int deg = degs[n];
  int limit = beg + deg;
  int end = beg + ((deg + 15) & ~15);
  const float* __restrict__ as = a_src + (size_t)h * N_NODES;
  float adn = a_dst[(size_t)h * N_NODES + n];
  const __half* __restrict__ hh = h1 + h * 64 + cg * 8;
  float4 aclo = make_float4(0.f, 0.f, 0.f, 0.f), achi = aclo;
  float s = 0.f;
  int e = beg + sub;
  bool va = e < limit, vb = e + 8 < limit;
  int t0 = csr[e], t1 = csr[e + 8];
  unsigned i0 = va ? (unsigned)t0 : 0u, i1 = vb ? (unsigned)t1 : 0u;
  float v0 = as[i0], v1 = as[i1];
  for (;;) {
    float4 galo, gahi, gblo, gbhi;
    ld_half8(hh + i0 * 320u, galo, gahi);
    ld_half8(hh + i1 * 320u, gblo, gbhi);
    float pa = va ? lrelu_exp(v0 + adn) : 0.f;
    float pb = vb ? lrelu_exp(v1 + adn) : 0.f;
    e += 16;
    bool more = e < end;
    if (more) {
      va = e < limit; vb = e + 8 < limit;
      t0 = csr[e]; t1 = csr[e + 8];
      i0 = va ? (unsigned)t0 : 0u; i1 = vb ? (unsigned)t1 : 0u;
      v0 = as[i0]; v1 = as[i1];
    }
    s += pa + pb;
    aclo.x = fmaf(pb, gblo.x, fmaf(pa, galo.x, aclo.x));
    aclo.y = fmaf(pb, gblo.y, fmaf(pa, galo.y, aclo.y));
    aclo.z = fmaf(pb, gblo.z, fmaf(pa, galo.z, aclo.z));
    aclo.w = fmaf(pb, gblo.w, fmaf(pa, galo.w, aclo.w));
    achi.x = fmaf(pb, gbhi.x, fmaf(pa, gahi.x, achi.x));
    achi.y = fmaf(pb, gbhi.y, fmaf(pa, gahi.y, achi.y));
    achi.z = fmaf(pb, gbhi.z, fmaf(pa, gahi.z, achi.z));
    achi.w = fmaf(pb, gbhi.w, fmaf(pa, gahi.w, achi.w));
    if (!more) break;
  }
#pragma unroll
  for (int m = 8; m <= 32; m <<= 1) {
    aclo.x += __shfl_xor(aclo.x, m);
    aclo.y += __shfl_xor(aclo.y, m);
    aclo.z += __shfl_xor(aclo.z, m);
    aclo.w += __shfl_xor(aclo.w, m);
    achi.x += __shfl_xor(achi.x, m);
    achi.y += __shfl_xor(achi.y, m);
    achi.z += __shfl_xor(achi.z, m);
    achi.w += __shfl_xor(achi.w, m);
    s += __shfl_xor(s, m);
  }
  if (sub == 0) {
    float inv = 1.f / (s + 1e-16f);
    const float* bp = b1 + h * 64 + cg * 8;
    float4 b_lo = *reinterpret_cast<const float4*>(bp);
    float4 b_hi = *reinterpret_cast<const float4*>(bp + 4);
    float4 olo, ohi;
    olo.x = fmaxf(fmaf(aclo.x, inv, b_lo.x), 0.f);
    olo.y = fmaxf(fmaf(aclo.y, inv, b_lo.y), 0.f);
    olo.z = fmaxf(fmaf(aclo.z, inv, b_lo.z), 0.f);
    olo.w = fmaxf(fmaf(aclo.w, inv, b_lo.w), 0.f);
    ohi.x = fmaxf(fmaf(achi.x, inv, b_hi.x), 0.f);
    ohi.y = fmaxf(fmaf(achi.y, inv, b_hi.y), 0.f);
    ohi.z = fmaxf(fmaf(achi.z, inv, b_hi.z), 0.f);
    ohi.w = fmaxf(fmaf(achi.w, inv, b_hi.w), 0.f);
    st_half8(&out1h[(size_t)n * 320 + h * 64 + cg * 8], olo, ohi);
  }
}

__global__ __launch_bounds__(256) void k_agg2(const __half* __restrict__ h2, const float* __restrict__ a_src,
                                              const float* __restrict__ a_dst, const float* __restrict__ b2,
                                              const int* __restrict__ degs, const int* __restrict__ csr,
                                              float* __restrict__ out) {
  int lane = threadIdx.x & 63, wid = threadIdx.x >> 6;
  int n = blockIdx.x * 4 + wid;
  int sub = lane >> 3;
  int cg = lane & 7;
  int beg = n << 7;
  int deg = degs[n];
  int limit = beg + deg;
  int end = beg + ((deg + 15) & ~15);
  float adn = a_dst[n];
  const __half* __restrict__ hh = h2 + cg * 8;
  float4 aclo = make_float4(0.f, 0.f, 0.f, 0.f), achi = aclo;
  float s = 0.f;
  int e = beg + sub;
  bool va = e < limit, vb = e + 8 < limit;
  int t0 = csr[e], t1 = csr[e + 8];
  unsigned i0 = va ? (unsigned)t0 : 0u, i1 = vb ? (unsigned)t1 : 0u;
  float v0 = a_src[i0], v1 = a_src[i1];
  for (;;) {
    float4 galo, gahi, gblo, gbhi;
    ld_half8(hh + i0 * 64u, galo, gahi);
    ld_half8(hh + i1 * 64u, gblo, gbhi);
    float pa = va ? lrelu_exp(v0 + adn) : 0.f;
    float pb = vb ? lrelu_exp(v1 + adn) : 0.f;
    e += 16;
    bool more = e < end;
    if (more) {
      va = e < limit; vb = e + 8 < limit;
      t0 = csr[e]; t1 = csr[e + 8];
      i0 = va ? (unsigned)t0 : 0u; i1 = vb ? (unsigned)t1 : 0u;
      v0 = a_src[i0]; v1 = a_src[i1];
    }
    s += pa + pb;
    aclo.x = fmaf(pb, gblo.x, fmaf(pa, galo.x, aclo.x));
    aclo.y = fmaf(pb, gblo.y, fmaf(pa, galo.y, aclo.y));
    aclo.z = fmaf(pb, gblo.z, fmaf(pa, galo.z, aclo.z));
    aclo.w = fmaf(pb, gblo.w, fmaf(pa, galo.w, aclo.w));
    achi.x = fmaf(pb, gbhi.x, fmaf(pa, gahi.x, achi.x));
    achi.y = fmaf(pb, gbhi.y, fmaf(pa, gahi.y, achi.y));
    achi.z = fmaf(pb, gbhi.z, fmaf(pa, gahi.z, achi.z));
    achi.w = fmaf(pb, gbhi.w, fmaf(pa, gahi.w, achi.w));
    if (!more) break;
  }
#pragma unroll
  for (int m = 8; m <= 32; m <<= 1) {
    aclo.x += __shfl_xor(aclo.x, m);
    aclo.y += __shfl_xor(aclo.y, m);
    aclo.z += __shfl_xor(aclo.z, m);
    aclo.w += __shfl_xor(aclo.w, m);
    achi.x += __shfl_xor(achi.x, m);
    achi.y += __shfl_xor(achi.y, m);
    achi.z += __shfl_xor(achi.z, m);
    achi.w += __shfl_xor(achi.w, m);
    s += __shfl_xor(s, m);
  }
  if (sub == 0) {
    float inv = 1.f / (s + 1e-16f);
    const float* bp = b2 + cg * 8;
    float4 b_lo = *reinterpret_cast<const float4*>(bp);
    float4 b_hi = *reinterpret_cast<const float4*>(bp + 4);
    float4 olo, ohi;
    olo.x = fmaxf(fmaf(aclo.x, inv, b_lo.x), 0.f);
    olo.y = fmaxf(fmaf(aclo.y, inv, b_lo.y), 0.f);
    olo.z = fmaxf(fmaf(aclo.z, inv, b_lo.z), 0.f);
    olo.w = fmaxf(fmaf(aclo.w, inv, b_lo.w), 0.f);
    ohi.x = fmaxf(fmaf(achi.x, inv, b_hi.x), 0.f);
    ohi.y = fmaxf(fmaf(achi.y, inv, b_hi.y), 0.f);
    ohi.z = fmaxf(fmaf(achi.z, inv, b_hi.z), 0.f);
    ohi.w = fmaxf(fmaf(achi.w, inv, b_hi.w), 0.f);
    float* op = &out[(size_t)n * 64 + cg * 8];
    *reinterpret_cast<float4*>(op) = olo;
    *reinterpret_cast<float4*>(op + 4) = ohi;
  }
}

// ---- layer 2 GEMM: split-K via fdot2 (fp16 out1h, fp16 W2t), partials fp32 ----

__global__ __launch_bounds__(256) void k_gemm2(const __half* __restrict__ out1h, const __half* __restrict__ W2t,
                                               float* __restrict__ h2part) {
  __shared__ __half xs_h[64][72];      // row stride 144B (9x16B)
  int t = threadIdx.x;
  int rb = blockIdx.x * 64;
  int kc = blockIdx.y;
#pragma unroll
  for (int i = 0; i < 2; ++i) {
    int idx = t + 256 * i;             // 512 chunks: 64 rows x 8 k-octets
    int row = idx >> 3, ko = idx & 7;
    int gr = rb + row;
    uint4 v = make_uint4(0, 0, 0, 0);
    if (gr < N_NODES) v = *reinterpret_cast<const uint4*>(&out1h[(size_t)gr * 320 + kc * 64 + ko * 8]);
    *reinterpret_cast<uint4*>(&xs_h[row][ko * 8]) = v;
  }
  __syncthreads();
  int cg = t & 15, rg = t >> 4;
  int c0 = cg * 4, r0 = rg * 4;
  const __half* __restrict__ wt = W2t + (size_t)c0 * 320 + kc * 64;
  float4 a0 = make_float4(0.f, 0.f, 0.f, 0.f), a1 = a0, a2 = a0, a3 = a0;
#pragma unroll
  for (int ko = 0; ko < 8; ++ko) {
    uint4 x0 = *reinterpret_cast<const uint4*>(&xs_h[r0 + 0][ko * 8]);
    uint4 x1 = *reinterpret_cast<const uint4*>(&xs_h[r0 + 1][ko * 8]);
    uint4 x2 = *reinterpret_cast<const uint4*>(&xs_h[r0 + 2][ko * 8]);
    uint4 x3 = *reinterpret_cast<const uint4*>(&xs_h[r0 + 3][ko * 8]);
    uint4 w0 = *reinterpret_cast<const uint4*>(wt + 0 * 320 + ko * 8);
    uint4 w1 = *reinterpret_cast<const uint4*>(wt + 1 * 320 + ko * 8);
    uint4 w2 = *reinterpret_cast<const uint4*>(wt + 2 * 320 + ko * 8);
    uint4 w3 = *reinterpret_cast<const uint4*>(wt + 3 * 320 + ko * 8);
    a0.x = dot8(x0, w0, a0.x); a0.y = dot8(x0, w1, a0.y); a0.z = dot8(x0, w2, a0.z); a0.w = dot8(x0, w3, a0.w);
    a1.x = dot8(x1, w0, a1.x); a1.y = dot8(x1, w1, a1.y); a1.z = dot8(x1, w2, a1.z); a1.w = dot8(x1, w3, a1.w);
    a2.x = dot8(x2, w0, a2.x); a2.y = dot8(x2, w1, a2.y); a2.z = dot8(x2, w2, a2.z); a2.w = dot8(x2, w3, a2.w);
    a3.x = dot8(x3, w0, a3.x); a3.y = dot8(x3, w1, a3.y); a3.z = dot8(x3, w2, a3.z); a3.w = dot8(x3, w3, a3.w);
  }
  float* __restrict__ hp = h2part + (size_t)kc * N_NODES * 64;
#pragma unroll
  for (int rr = 0; rr < 4; ++rr) {
    float4 ar = (rr == 0) ? a0 : (rr == 1) ? a1 : (rr == 2) ? a2 : a3;
    int gr = rb + r0 + rr;
    if (gr < N_NODES) *reinterpret_cast<float4*>(&hp[(size_t)gr * 64 + c0]) = ar;
  }
}

// ---- reduce 5 partials (fixed order) + att dots; h2 stored fp16 ----

__global__ __launch_bounds__(256) void k_hred2(const float* __restrict__ h2part,
                                               const float* __restrict__ att_src, const float* __restrict__ att_dst,
                                               __half* __restrict__ h2, float* __restrict__ a_src,
                                               float* __restrict__ a_dst) {
  int n = blockIdx.x * 4 + (threadIdx.x >> 6);
  int c = threadIdx.x & 63;
  if (n >= N_NODES) return;
  float v = 0.f;
#pragma unroll
  for (int kc = 0; kc < 5; ++kc) v += h2part[((size_t)kc * N_NODES + n) * 64 + c];
  float vs = v * att_src[c], vd = v * att_dst[c];
  float vnext = __shfl_down(v, 1);
  if ((c & 1) == 0) {
    __half2 p = __float22half2_rn(make_float2(v, vnext));
    *reinterpret_cast<unsigned*>(&h2[(size_t)n * 64 + c]) = *reinterpret_cast<const unsigned*>(&p);
  }
  for (int off = 32; off; off >>= 1) {
    vs += __shfl_down(vs, off);
    vd += __shfl_down(vd, off);
  }
  if (c == 0) { a_src[n] = vs; a_dst[n] = vd; }
}

// ---------------- launch ----------------

extern "C" void kernel_launch(void* const* d_in, const int* in_sizes, int n_in,
                              void* d_out, int out_size, void* d_ws, size_t ws_size,
                              hipStream_t stream) {
  (void)in_sizes; (void)n_in; (void)out_size; (void)ws_size;
  const float* x    = (const float*)d_in[0];
  const int*   ei   = (const int*)d_in[1];
  const float* W1   = (const float*)d_in[2];
  const float* as1w = (const float*)d_in[3];
  const float* ad1w = (const float*)d_in[4];
  const float* b1   = (const float*)d_in[5];
  const float* W2   = (const float*)d_in[6];
  const float* as2w = (const float*)d_in[7];
  const float* ad2w = (const float*)d_in[8];
  const float* b2   = (const float*)d_in[9];
  float* out = (float*)d_out;

  char* ws = (char*)d_ws;
  size_t off = 0;
  auto alloc = [&](size_t bytes) -> void* {
    void* p = ws + off;
    off += (bytes + 255) & ~(size_t)255;
    return p;
  };
  __half* xh     = (__half*)alloc((size_t)N_NODES * 128 * 2);
  __half* W1t    = (__half*)alloc((size_t)320 * 128 * 2);
  __half* W2t    = (__half*)alloc((size_t)64 * 320 * 2);
  __half* h1     = (__half*)alloc((size_t)N_NODES * 320 * 2);
  __half* out1h  = (__half*)alloc((size_t)N_NODES * 320 * 2);
  __half* h2     = (__half*)alloc((size_t)N_NODES * 64 * 2);
  float*  h2part = (float*)alloc((size_t)5 * N_NODES * 64 * 4);
  float*  a_src1 = (float*)alloc((size_t)5 * N_NODES * 4);
  float*  a_dst1 = (float*)alloc((size_t)5 * N_NODES * 4);
  float*  a_src2 = (float*)alloc((size_t)N_NODES * 4);
  float*  a_dst2 = (float*)alloc((size_t)N_NODES * 4);
  int*    cursor = (int*)alloc((size_t)N_NODES * 4);
  int*    csr    = (int*)alloc((size_t)N_NODES * CAP * 4);  // pad slots never interpreted: no init

  k_init<<<NB_INIT, 256, 0, stream>>>(cursor, x, xh, W1, W1t, W2, W2t);
  k_gemm1_scatter<<<NB_G1 + NB_SCT, 256, 0, stream>>>(xh, W1t, as1w, ad1w, h1, a_src1, a_dst1,
                                                      ei, cursor, csr);
  {
    dim3 g(N_NODES / 4, 5);
    k_agg1 <<<g, 256, 0, stream>>>(h1, a_src1, a_dst1, b1, cursor, csr, out1h);
  }
  {
    dim3 g((N_NODES + 63) / 64, 5);
    k_gemm2<<<g, 256, 0, stream>>>(out1h, W2t, h2part);
  }
  k_hred2<<<(N_NODES + 3) / 4, 256, 0, stream>>>(h2part, as2w, ad2w, h2, a_src2, a_dst2);
  k_agg2 <<<N_NODES / 4, 256, 0, stream>>>(h2, a_src2, a_dst2, b2, cursor, csr, out);
}

// Round 17
// 100.528 us; speedup vs baseline: 1.2179x; 1.2179x over previous
//
#include <hip/hip_runtime.h>
#include <hip/hip_fp16.h>
#include <math.h>

#define N_NODES 10000
#define N_EDGES 320000
#define ET (N_EDGES + N_NODES)        // edges + self-loops
#define CAP 128                       // per-node CSR bucket capacity (max deg ~60)
#define NB_G1 (157 * 5)               // gemm1 blocks in fused launch
#define NB_SCT ((ET + 255) / 256)     // scatter blocks in fused launch

__device__ __forceinline__ float lrelu_exp(float e) {
  e = (e > 0.f) ? e : 0.2f * e;   // leaky_relu
  return __expf(e);               // logits O(+-6): no max-shift needed
}

__device__ __forceinline__ void ld_half8(const __half* p, float4& lo, float4& hi) {
  uint4 u = *reinterpret_cast<const uint4*>(p);
  float2 f0 = __half22float2(*reinterpret_cast<const __half2*>(&u.x));
  float2 f1 = __half22float2(*reinterpret_cast<const __half2*>(&u.y));
  float2 f2 = __half22float2(*reinterpret_cast<const __half2*>(&u.z));
  float2 f3 = __half22float2(*reinterpret_cast<const __half2*>(&u.w));
  lo = make_float4(f0.x, f0.y, f1.x, f1.y);
  hi = make_float4(f2.x, f2.y, f3.x, f3.y);
}

__device__ __forceinline__ void st_half4(__half* p, float4 v) {
  __half2 lo = __float22half2_rn(make_float2(v.x, v.y));
  __half2 hi = __float22half2_rn(make_float2(v.z, v.w));
  uint2 u;
  u.x = *reinterpret_cast<const unsigned*>(&lo);
  u.y = *reinterpret_cast<const unsigned*>(&hi);
  *reinterpret_cast<uint2*>(p) = u;
}

// ---------------- init: zero cursor ----------------

__global__ __launch_bounds__(256) void k_init(int* __restrict__ cursor) {
  int i = blockIdx.x * 256 + threadIdx.x;
  if (i < N_NODES) cursor[i] = 0;
}

// ------- fused: gemm1 (blocks 0..784, h1 out in fp16) + bucket-scatter (rest) -------

__global__ __launch_bounds__(256) void k_gemm1_scatter(const float* __restrict__ x, const float* __restrict__ W1,
                                                       const float* __restrict__ att_src, const float* __restrict__ att_dst,
                                                       __half* __restrict__ h1, float* __restrict__ a_src,
                                                       float* __restrict__ a_dst,
                                                       const int* __restrict__ ei, int* __restrict__ cursor,
                                                       int* __restrict__ csr) {
  __shared__ float xs[128][65];
  int bid = blockIdx.x;
  int t = threadIdx.x;
  if (bid >= NB_G1) {                      // ---- scatter path ----
    int i = (bid - NB_G1) * 256 + t;
    if (i < ET) {
      int src, dst;
      if (i < N_EDGES) { src = ei[i]; dst = ei[N_EDGES + i]; }
      else             { src = dst = i - N_EDGES; }
      int pos = (dst << 7) + atomicAdd(&cursor[dst], 1);
      csr[pos] = src;
    }
    return;
  }
  // ---- gemm1 path: 64-row x 64-col tile, head = bid/157 ----
  int h = bid / 157;
  int rb = (bid % 157) * 64;
#pragma unroll
  for (int i = 0; i < 8; ++i) {
    int idx = t + 256 * i;
    int kq = (idx & 31) * 4;
    int row = idx >> 5;
    int gr = rb + row;
    float4 v = make_float4(0.f, 0.f, 0.f, 0.f);
    if (gr < N_NODES) v = *reinterpret_cast<const float4*>(&x[(size_t)gr * 128 + kq]);
    xs[kq + 0][row] = v.x; xs[kq + 1][row] = v.y; xs[kq + 2][row] = v.z; xs[kq + 3][row] = v.w;
  }
  __syncthreads();
  int cg = t & 15, rg = t >> 4;
  int c0 = cg * 4, r0 = rg * 4;
  const float* __restrict__ wp = W1 + h * 64 + c0;
  float4 a0 = make_float4(0.f,0.f,0.f,0.f), a1 = a0, a2 = a0, a3 = a0;
#pragma unroll 4
  for (int k = 0; k < 128; ++k) {
    float4 xv = *reinterpret_cast<const float4*>(&xs[k][r0]);
    float4 wv = *reinterpret_cast<const float4*>(&wp[(size_t)k * 320]);
    a0.x = fmaf(xv.x, wv.x, a0.x); a0.y = fmaf(xv.x, wv.y, a0.y); a0.z = fmaf(xv.x, wv.z, a0.z); a0.w = fmaf(xv.x, wv.w, a0.w);
    a1.x = fmaf(xv.y, wv.x, a1.x); a1.y = fmaf(xv.y, wv.y, a1.y); a1.z = fmaf(xv.y, wv.z, a1.z); a1.w = fmaf(xv.y, wv.w, a1.w);
    a2.x = fmaf(xv.z, wv.x, a2.x); a2.y = fmaf(xv.z, wv.y, a2.y); a2.z = fmaf(xv.z, wv.z, a2.z); a2.w = fmaf(xv.z, wv.w, a2.w);
    a3.x = fmaf(xv.w, wv.x, a3.x); a3.y = fmaf(xv.w, wv.y, a3.y); a3.z = fmaf(xv.w, wv.z, a3.z); a3.w = fmaf(xv.w, wv.w, a3.w);
  }
  float4 asv = *reinterpret_cast<const float4*>(&att_src[h * 64 + c0]);
  float4 adv = *reinterpret_cast<const float4*>(&att_dst[h * 64 + c0]);
#pragma unroll
  for (int rr = 0; rr < 4; ++rr) {
    float4 ar = (rr == 0) ? a0 : (rr == 1) ? a1 : (rr == 2) ? a2 : a3;
    float vs = ar.x * asv.x + ar.y * asv.y + ar.z * asv.z + ar.w * asv.w;
    float vd = ar.x * adv.x + ar.y * adv.y + ar.z * adv.z + ar.w * adv.w;
#pragma unroll
    for (int m = 1; m < 16; m <<= 1) { vs += __shfl_xor(vs, m); vd += __shfl_xor(vd, m); }
    int gr = rb + r0 + rr;
    if (gr < N_NODES) {
      if (cg == 0) { a_src[h * N_NODES + gr] = vs; a_dst[h * N_NODES + gr] = vd; }
      st_half4(&h1[(size_t)gr * 320 + h * 64 + c0], ar);   // fp16 storage: 128B/head-row
    }
  }
}

// ---- agg1: 8 edge-slots x 8 lanes/edge, 3-stage pipeline (idx +2, gather +1) ----

__global__ __launch_bounds__(256) void k_agg1(const __half* __restrict__ h1, const float* __restrict__ a_src,
                                              const float* __restrict__ a_dst, const float* __restrict__ b1,
                                              const int* __restrict__ degs, const int* __restrict__ csr,
                                              float* __restrict__ out1) {
  int lane = threadIdx.x & 63, wid = threadIdx.x >> 6;
  int n = blockIdx.x * 4 + wid;
  int h = blockIdx.y;
  int sub = lane >> 3;        // edge slot 0..7
  int cg = lane & 7;          // channel octet
  int beg = n << 7;
  int deg = degs[n];
  int limit = beg + deg;
  int end = beg + ((deg + 15) & ~15);
  const float* __restrict__ as = a_src + (size_t)h * N_NODES;
  float adn = a_dst[(size_t)h * N_NODES + n];
  const __half* __restrict__ hh = h1 + h * 64 + cg * 8;
  float4 aclo = make_float4(0.f, 0.f, 0.f, 0.f), achi = aclo;
  float s = 0.f;

  int e = beg + sub;
  // idx stage, iter 0
  bool va0 = e < limit, vb0 = e + 8 < limit;
  int t0 = csr[e], t1 = csr[e + 8];
  unsigned i0 = va0 ? (unsigned)t0 : 0u, i1 = vb0 ? (unsigned)t1 : 0u;
  float v0 = as[i0], v1 = as[i1];
  // gather stage, iter 0
  float4 galo, gahi, gblo, gbhi;
  ld_half8(hh + i0 * 320u, galo, gahi);
  ld_half8(hh + i1 * 320u, gblo, gbhi);
  // idx stage, iter 1
  int e1 = e + 16;
  bool more1 = e1 < end;
  bool va1 = false, vb1 = false;
  unsigned i2 = 0u, i3 = 0u;
  float v2 = 0.f, v3 = 0.f;
  if (more1) {
    va1 = e1 < limit; vb1 = e1 + 8 < limit;
    int u0 = csr[e1], u1 = csr[e1 + 8];
    i2 = va1 ? (unsigned)u0 : 0u; i3 = vb1 ? (unsigned)u1 : 0u;
    v2 = as[i2]; v3 = as[i3];
  }
  for (;;) {
    // issue next iteration's gathers early (hidden under this iter's compute)
    float4 nalo = galo, nahi = gahi, nblo = gblo, nbhi = gbhi;
    if (more1) {
      ld_half8(hh + i2 * 320u, nalo, nahi);
      ld_half8(hh + i3 * 320u, nblo, nbhi);
    }
    // idx prefetch, 2 ahead
    int e2 = e1 + 16;
    bool more2 = e2 < end;
    bool va2 = false, vb2 = false;
    unsigned i4 = 0u, i5 = 0u;
    float v4 = 0.f, v5 = 0.f;
    if (more2) {
      va2 = e2 < limit; vb2 = e2 + 8 < limit;
      int u0 = csr[e2], u1 = csr[e2 + 8];
      i4 = va2 ? (unsigned)u0 : 0u; i5 = vb2 ? (unsigned)u1 : 0u;
      v4 = as[i4]; v5 = as[i5];
    }
    // compute current iteration (gathers issued one iteration ago)
    float pa = va0 ? lrelu_exp(v0 + adn) : 0.f;
    float pb = vb0 ? lrelu_exp(v1 + adn) : 0.f;
    s += pa + pb;
    aclo.x = fmaf(pb, gblo.x, fmaf(pa, galo.x, aclo.x));
    aclo.y = fmaf(pb, gblo.y, fmaf(pa, galo.y, aclo.y));
    aclo.z = fmaf(pb, gblo.z, fmaf(pa, galo.z, aclo.z));
    aclo.w = fmaf(pb, gblo.w, fmaf(pa, galo.w, aclo.w));
    achi.x = fmaf(pb, gbhi.x, fmaf(pa, gahi.x, achi.x));
    achi.y = fmaf(pb, gbhi.y, fmaf(pa, gahi.y, achi.y));
    achi.z = fmaf(pb, gbhi.z, fmaf(pa, gahi.z, achi.z));
    achi.w = fmaf(pb, gbhi.w, fmaf(pa, gahi.w, achi.w));
    if (!more1) break;
    // rotate pipeline
    va0 = va1; vb0 = vb1; v0 = v2; v1 = v3;
    galo = nalo; gahi = nahi; gblo = nblo; gbhi = nbhi;
    va1 = va2; vb1 = vb2; i2 = i4; i3 = i5; v2 = v4; v3 = v5;
    e1 = e2; more1 = more2;
  }
#pragma unroll
  for (int m = 8; m <= 32; m <<= 1) {    // reduce across 8 edge-slots
    aclo.x += __shfl_xor(aclo.x, m);
    aclo.y += __shfl_xor(aclo.y, m);
    aclo.z += __shfl_xor(aclo.z, m);
    aclo.w += __shfl_xor(aclo.w, m);
    achi.x += __shfl_xor(achi.x, m);
    achi.y += __shfl_xor(achi.y, m);
    achi.z += __shfl_xor(achi.z, m);
    achi.w += __shfl_xor(achi.w, m);
    s += __shfl_xor(s, m);
  }
  if (sub == 0) {
    float inv = 1.f / (s + 1e-16f);
    const float* bp = b1 + h * 64 + cg * 8;
    float4 b_lo = *reinterpret_cast<const float4*>(bp);
    float4 b_hi = *reinterpret_cast<const float4*>(bp + 4);
    float4 olo, ohi;
    olo.x = fmaxf(fmaf(aclo.x, inv, b_lo.x), 0.f);
    olo.y = fmaxf(fmaf(aclo.y, inv, b_lo.y), 0.f);
    olo.z = fmaxf(fmaf(aclo.z, inv, b_lo.z), 0.f);
    olo.w = fmaxf(fmaf(aclo.w, inv, b_lo.w), 0.f);
    ohi.x = fmaxf(fmaf(achi.x, inv, b_hi.x), 0.f);
    ohi.y = fmaxf(fmaf(achi.y, inv, b_hi.y), 0.f);
    ohi.z = fmaxf(fmaf(achi.z, inv, b_hi.z), 0.f);
    ohi.w = fmaxf(fmaf(achi.w, inv, b_hi.w), 0.f);
    float* op = &out1[(size_t)n * 320 + h * 64 + cg * 8];
    *reinterpret_cast<float4*>(op) = olo;
    *reinterpret_cast<float4*>(op + 4) = ohi;
  }
}

__global__ __launch_bounds__(256) void k_agg2(const __half* __restrict__ h2, const float* __restrict__ a_src,
                                              const float* __restrict__ a_dst, const float* __restrict__ b2,
                                              const int* __restrict__ degs, const int* __restrict__ csr,
                                              float* __restrict__ out) {
  int lane = threadIdx.x & 63, wid = threadIdx.x >> 6;
  int n = blockIdx.x * 4 + wid;
  int sub = lane >> 3;
  int cg = lane & 7;
  int beg = n << 7;
  int deg = degs[n];
  int limit = beg + deg;
  int end = beg + ((deg + 15) & ~15);
  float adn = a_dst[n];
  const __half* __restrict__ hh = h2 + cg * 8;
  float4 aclo = make_float4(0.f, 0.f, 0.f, 0.f), achi = aclo;
  float s = 0.f;

  int e = beg + sub;
  bool va0 = e < limit, vb0 = e + 8 < limit;
  int t0 = csr[e], t1 = csr[e + 8];
  unsigned i0 = va0 ? (unsigned)t0 : 0u, i1 = vb0 ? (unsigned)t1 : 0u;
  float v0 = a_src[i0], v1 = a_src[i1];
  float4 galo, gahi, gblo, gbhi;
  ld_half8(hh + i0 * 64u, galo, gahi);
  ld_half8(hh + i1 * 64u, gblo, gbhi);
  int e1 = e + 16;
  bool more1 = e1 < end;
  bool va1 = false, vb1 = false;
  unsigned i2 = 0u, i3 = 0u;
  float v2 = 0.f, v3 = 0.f;
  if (more1) {
    va1 = e1 < limit; vb1 = e1 + 8 < limit;
    int u0 = csr[e1], u1 = csr[e1 + 8];
    i2 = va1 ? (unsigned)u0 : 0u; i3 = vb1 ? (unsigned)u1 : 0u;
    v2 = a_src[i2]; v3 = a_src[i3];
  }
  for (;;) {
    float4 nalo = galo, nahi = gahi, nblo = gblo, nbhi = gbhi;
    if (more1) {
      ld_half8(hh + i2 * 64u, nalo, nahi);
      ld_half8(hh + i3 * 64u, nblo, nbhi);
    }
    int e2 = e1 + 16;
    bool more2 = e2 < end;
    bool va2 = false, vb2 = false;
    unsigned i4 = 0u, i5 = 0u;
    float v4 = 0.f, v5 = 0.f;
    if (more2) {
      va2 = e2 < limit; vb2 = e2 + 8 < limit;
      int u0 = csr[e2], u1 = csr[e2 + 8];
      i4 = va2 ? (unsigned)u0 : 0u; i5 = vb2 ? (unsigned)u1 : 0u;
      v4 = a_src[i4]; v5 = a_src[i5];
    }
    float pa = va0 ? lrelu_exp(v0 + adn) : 0.f;
    float pb = vb0 ? lrelu_exp(v1 + adn) : 0.f;
    s += pa + pb;
    aclo.x = fmaf(pb, gblo.x, fmaf(pa, galo.x, aclo.x));
    aclo.y = fmaf(pb, gblo.y, fmaf(pa, galo.y, aclo.y));
    aclo.z = fmaf(pb, gblo.z, fmaf(pa, galo.z, aclo.z));
    aclo.w = fmaf(pb, gblo.w, fmaf(pa, galo.w, aclo.w));
    achi.x = fmaf(pb, gbhi.x, fmaf(pa, gahi.x, achi.x));
    achi.y = fmaf(pb, gbhi.y, fmaf(pa, gahi.y, achi.y));
    achi.z = fmaf(pb, gbhi.z, fmaf(pa, gahi.z, achi.z));
    achi.w = fmaf(pb, gbhi.w, fmaf(pa, gahi.w, achi.w));
    if (!more1) break;
    va0 = va1; vb0 = vb1; v0 = v2; v1 = v3;
    galo = nalo; gahi = nahi; gblo = nblo; gbhi = nbhi;
    va1 = va2; vb1 = vb2; i2 = i4; i3 = i5; v2 = v4; v3 = v5;
    e1 = e2; more1 = more2;
  }
#pragma unroll
  for (int m = 8; m <= 32; m <<= 1) {
    aclo.x += __shfl_xor(aclo.x, m);
    aclo.y += __shfl_xor(aclo.y, m);
    aclo.z += __shfl_xor(aclo.z, m);
    aclo.w += __shfl_xor(aclo.w, m);
    achi.x += __shfl_xor(achi.x, m);
    achi.y += __shfl_xor(achi.y, m);
    achi.z += __shfl_xor(achi.z, m);
    achi.w += __shfl_xor(achi.w, m);
    s += __shfl_xor(s, m);
  }
  if (sub == 0) {
    float inv = 1.f / (s + 1e-16f);
    const float* bp = b2 + cg * 8;
    float4 b_lo = *reinterpret_cast<const float4*>(bp);
    float4 b_hi = *reinterpret_cast<const float4*>(bp + 4);
    float4 olo, ohi;
    olo.x = fmaxf(fmaf(aclo.x, inv, b_lo.x), 0.f);
    olo.y = fmaxf(fmaf(aclo.y, inv, b_lo.y), 0.f);
    olo.z = fmaxf(fmaf(aclo.z, inv, b_lo.z), 0.f);
    olo.w = fmaxf(fmaf(aclo.w, inv, b_lo.w), 0.f);
    ohi.x = fmaxf(fmaf(achi.x, inv, b_hi.x), 0.f);
    ohi.y = fmaxf(fmaf(achi.y, inv, b_hi.y), 0.f);
    ohi.z = fmaxf(fmaf(achi.z, inv, b_hi.z), 0.f);
    ohi.w = fmaxf(fmaf(achi.w, inv, b_hi.w), 0.f);
    float* op = &out[(size_t)n * 64 + cg * 8];
    *reinterpret_cast<float4*>(op) = olo;
    *reinterpret_cast<float4*>(op + 4) = ohi;
  }
}

// ---- layer 2 GEMM: split-K, blockIdx.y = K-chunk (grid 157x5), partials out ----

__global__ __launch_bounds__(256) void k_gemm2(const float* __restrict__ out1, const float* __restrict__ W2,
                                               float* __restrict__ h2part) {
  __shared__ float xs[64][65];
  int t = threadIdx.x;
  int rb = blockIdx.x * 64;
  int kc = blockIdx.y;
#pragma unroll
  for (int i = 0; i < 4; ++i) {
    int idx = t + 256 * i;
    int kq = (idx & 15) * 4;
    int row = idx >> 4;
    int gr = rb + row;
    float4 v = make_float4(0.f, 0.f, 0.f, 0.f);
    if (gr < N_NODES) v = *reinterpret_cast<const float4*>(&out1[(size_t)gr * 320 + kc * 64 + kq]);
    xs[kq + 0][row] = v.x; xs[kq + 1][row] = v.y; xs[kq + 2][row] = v.z; xs[kq + 3][row] = v.w;
  }
  __syncthreads();
  int cg = t & 15, rg = t >> 4;
  int c0 = cg * 4, r0 = rg * 4;
  const float* __restrict__ wp = W2 + (size_t)kc * 64 * 64 + c0;
  float4 a0 = make_float4(0.f,0.f,0.f,0.f), a1 = a0, a2 = a0, a3 = a0;
#pragma unroll 4
  for (int k = 0; k < 64; ++k) {
    float4 xv = *reinterpret_cast<const float4*>(&xs[k][r0]);
    float4 wv = *reinterpret_cast<const float4*>(&wp[(size_t)k * 64]);
    a0.x = fmaf(xv.x, wv.x, a0.x); a0.y = fmaf(xv.x, wv.y, a0.y); a0.z = fmaf(xv.x, wv.z, a0.z); a0.w = fmaf(xv.x, wv.w, a0.w);
    a1.x = fmaf(xv.y, wv.x, a1.x); a1.y = fmaf(xv.y, wv.y, a1.y); a1.z = fmaf(xv.y, wv.z, a1.z); a1.w = fmaf(xv.y, wv.w, a1.w);
    a2.x = fmaf(xv.z, wv.x, a2.x); a2.y = fmaf(xv.z, wv.y, a2.y); a2.z = fmaf(xv.z, wv.z, a2.z); a2.w = fmaf(xv.z, wv.w, a2.w);
    a3.x = fmaf(xv.w, wv.x, a3.x); a3.y = fmaf(xv.w, wv.y, a3.y); a3.z = fmaf(xv.w, wv.z, a3.z); a3.w = fmaf(xv.w, wv.w, a3.w);
  }
  float* __restrict__ hp = h2part + (size_t)kc * N_NODES * 64;
#pragma unroll
  for (int rr = 0; rr < 4; ++rr) {
    float4 ar = (rr == 0) ? a0 : (rr == 1) ? a1 : (rr == 2) ? a2 : a3;
    int gr = rb + r0 + rr;
    if (gr < N_NODES) *reinterpret_cast<float4*>(&hp[(size_t)gr * 64 + c0]) = ar;
  }
}

// ---- reduce 5 partials (fixed order) + att dots; h2 stored fp16 ----

__global__ __launch_bounds__(256) void k_hred2(const float* __restrict__ h2part,
                                               const float* __restrict__ att_src, const float* __restrict__ att_dst,
                                               __half* __restrict__ h2, float* __restrict__ a_src,
                                               float* __restrict__ a_dst) {
  int n = blockIdx.x * 4 + (threadIdx.x >> 6);
  int c = threadIdx.x & 63;
  if (n >= N_NODES) return;
  float v = 0.f;
#pragma unroll
  for (int kc = 0; kc < 5; ++kc) v += h2part[((size_t)kc * N_NODES + n) * 64 + c];
  float vs = v * att_src[c], vd = v * att_dst[c];
  float vnext = __shfl_down(v, 1);
  if ((c & 1) == 0) {
    __half2 p = __float22half2_rn(make_float2(v, vnext));
    *reinterpret_cast<unsigned*>(&h2[(size_t)n * 64 + c]) = *reinterpret_cast<const unsigned*>(&p);
  }
  for (int off = 32; off; off >>= 1) {
    vs += __shfl_down(vs, off);
    vd += __shfl_down(vd, off);
  }
  if (c == 0) { a_src[n] = vs; a_dst[n] = vd; }
}

// ---------------- launch ----------------

extern "C" void kernel_launch(void* const* d_in, const int* in_sizes, int n_in,
                              void* d_out, int out_size, void* d_ws, size_t ws_size,
                              hipStream_t stream) {
  (void)in_sizes; (void)n_in; (void)out_size; (void)ws_size;
  const float* x    = (const float*)d_in[0];
  const int*   ei   = (const int*)d_in[1];
  const float* W1   = (const float*)d_in[2];
  const float* as1w = (const float*)d_in[3];
  const float* ad1w = (const float*)d_in[4];
  const float* b1   = (const float*)d_in[5];
  const float* W2   = (const float*)d_in[6];
  const float* as2w = (const float*)d_in[7];
  const float* ad2w = (const float*)d_in[8];
  const float* b2   = (const float*)d_in[9];
  float* out = (float*)d_out;

  char* ws = (char*)d_ws;
  size_t off = 0;
  auto alloc = [&](size_t bytes) -> void* {
    void* p = ws + off;
    off += (bytes + 255) & ~(size_t)255;
    return p;
  };
  __half* h1     = (__half*)alloc((size_t)N_NODES * 320 * 2);
  float*  out1   = (float*)alloc((size_t)N_NODES * 320 * 4);
  __half* h2     = (__half*)alloc((size_t)N_NODES * 64 * 2);
  float*  h2part = (float*)alloc((size_t)5 * N_NODES * 64 * 4);
  float*  a_src1 = (float*)alloc((size_t)5 * N_NODES * 4);
  float*  a_dst1 = (float*)alloc((size_t)5 * N_NODES * 4);
  float*  a_src2 = (float*)alloc((size_t)N_NODES * 4);
  float*  a_dst2 = (float*)alloc((size_t)N_NODES * 4);
  int*    cursor = (int*)alloc((size_t)N_NODES * 4);
  int*    csr    = (int*)alloc((size_t)N_NODES * CAP * 4);  // pad slots never interpreted: no init

  k_init<<<(N_NODES + 255) / 256, 256, 0, stream>>>(cursor);
  k_gemm1_scatter<<<NB_G1 + NB_SCT, 256, 0, stream>>>(x, W1, as1w, ad1w, h1, a_src1, a_dst1,
                                                      ei, cursor, csr);
  {
    dim3 g(N_NODES / 4, 5);
    k_agg1 <<<g, 256, 0, stream>>>(h1, a_src1, a_dst1, b1, cursor, csr, out1);
  }
  {
    dim3 g((N_NODES + 63) / 64, 5);
    k_gemm2<<<g, 256, 0, stream>>>(out1, W2, h2part);
  }
  k_hred2<<<(N_NODES + 3) / 4, 256, 0, stream>>>(h2part, as2w, ad2w, h2, a_src2, a_dst2);
  k_agg2 <<<N_NODES / 4, 256, 0, stream>>>(h2, a_src2, a_dst2, b2, cursor, csr, out);
}

// Round 18
// 96.654 us; speedup vs baseline: 1.2667x; 1.0401x over previous
//
#include <hip/hip_runtime.h>
#include <hip/hip_fp16.h>
#include <math.h>

#define N_NODES 10000
#define N_EDGES 320000
#define ET (N_EDGES + N_NODES)        // edges + self-loops
#define CAP 128                       // per-node CSR bucket capacity (max deg ~60)
#define NB_G1 (157 * 5)               // gemm1 blocks in fused launch
#define NB_SCT ((ET + 255) / 256)     // scatter blocks in fused launch

__device__ __forceinline__ float lrelu_exp(float e) {
  e = (e > 0.f) ? e : 0.2f * e;   // leaky_relu
  return __expf(e);               // logits O(+-6): no max-shift needed
}

__device__ __forceinline__ void ld_half8(const __half* p, float4& lo, float4& hi) {
  uint4 u = *reinterpret_cast<const uint4*>(p);   // 16B: one line-segment per edge-row
  float2 f0 = __half22float2(*reinterpret_cast<const __half2*>(&u.x));
  float2 f1 = __half22float2(*reinterpret_cast<const __half2*>(&u.y));
  float2 f2 = __half22float2(*reinterpret_cast<const __half2*>(&u.z));
  float2 f3 = __half22float2(*reinterpret_cast<const __half2*>(&u.w));
  lo = make_float4(f0.x, f0.y, f1.x, f1.y);
  hi = make_float4(f2.x, f2.y, f3.x, f3.y);
}

__device__ __forceinline__ void st_half4(__half* p, float4 v) {
  __half2 lo = __float22half2_rn(make_float2(v.x, v.y));
  __half2 hi = __float22half2_rn(make_float2(v.z, v.w));
  uint2 u;
  u.x = *reinterpret_cast<const unsigned*>(&lo);
  u.y = *reinterpret_cast<const unsigned*>(&hi);
  *reinterpret_cast<uint2*>(p) = u;
}

// ---------------- init: zero cursor ----------------

__global__ __launch_bounds__(256) void k_init(int* __restrict__ cursor) {
  int i = blockIdx.x * 256 + threadIdx.x;
  if (i < N_NODES) cursor[i] = 0;
}

// ------- fused: gemm1 (blocks 0..784, h1 out in fp16) + bucket-scatter (rest) -------

__global__ __launch_bounds__(256) void k_gemm1_scatter(const float* __restrict__ x, const float* __restrict__ W1,
                                                       const float* __restrict__ att_src, const float* __restrict__ att_dst,
                                                       __half* __restrict__ h1, float* __restrict__ a_src,
                                                       float* __restrict__ a_dst,
                                                       const int* __restrict__ ei, int* __restrict__ cursor,
                                                       int* __restrict__ csr) {
  __shared__ float xs[128][65];
  int bid = blockIdx.x;
  int t = threadIdx.x;
  if (bid >= NB_G1) {                      // ---- scatter path ----
    int i = (bid - NB_G1) * 256 + t;
    if (i < ET) {
      int src, dst;
      if (i < N_EDGES) { src = ei[i]; dst = ei[N_EDGES + i]; }
      else             { src = dst = i - N_EDGES; }
      int pos = (dst << 7) + atomicAdd(&cursor[dst], 1);
      csr[pos] = src;
    }
    return;
  }
  // ---- gemm1 path: 64-row x 64-col tile, head = bid/157 ----
  int h = bid / 157;
  int rb = (bid % 157) * 64;
#pragma unroll
  for (int i = 0; i < 8; ++i) {
    int idx = t + 256 * i;
    int kq = (idx & 31) * 4;
    int row = idx >> 5;
    int gr = rb + row;
    float4 v = make_float4(0.f, 0.f, 0.f, 0.f);
    if (gr < N_NODES) v = *reinterpret_cast<const float4*>(&x[(size_t)gr * 128 + kq]);
    xs[kq + 0][row] = v.x; xs[kq + 1][row] = v.y; xs[kq + 2][row] = v.z; xs[kq + 3][row] = v.w;
  }
  __syncthreads();
  int cg = t & 15, rg = t >> 4;
  int c0 = cg * 4, r0 = rg * 4;
  const float* __restrict__ wp = W1 + h * 64 + c0;
  float4 a0 = make_float4(0.f,0.f,0.f,0.f), a1 = a0, a2 = a0, a3 = a0;
#pragma unroll 4
  for (int k = 0; k < 128; ++k) {
    float4 xv = *reinterpret_cast<const float4*>(&xs[k][r0]);
    float4 wv = *reinterpret_cast<const float4*>(&wp[(size_t)k * 320]);
    a0.x = fmaf(xv.x, wv.x, a0.x); a0.y = fmaf(xv.x, wv.y, a0.y); a0.z = fmaf(xv.x, wv.z, a0.z); a0.w = fmaf(xv.x, wv.w, a0.w);
    a1.x = fmaf(xv.y, wv.x, a1.x); a1.y = fmaf(xv.y, wv.y, a1.y); a1.z = fmaf(xv.y, wv.z, a1.z); a1.w = fmaf(xv.y, wv.w, a1.w);
    a2.x = fmaf(xv.z, wv.x, a2.x); a2.y = fmaf(xv.z, wv.y, a2.y); a2.z = fmaf(xv.z, wv.z, a2.z); a2.w = fmaf(xv.z, wv.w, a2.w);
    a3.x = fmaf(xv.w, wv.x, a3.x); a3.y = fmaf(xv.w, wv.y, a3.y); a3.z = fmaf(xv.w, wv.z, a3.z); a3.w = fmaf(xv.w, wv.w, a3.w);
  }
  float4 asv = *reinterpret_cast<const float4*>(&att_src[h * 64 + c0]);
  float4 adv = *reinterpret_cast<const float4*>(&att_dst[h * 64 + c0]);
#pragma unroll
  for (int rr = 0; rr < 4; ++rr) {
    float4 ar = (rr == 0) ? a0 : (rr == 1) ? a1 : (rr == 2) ? a2 : a3;
    float vs = ar.x * asv.x + ar.y * asv.y + ar.z * asv.z + ar.w * asv.w;
    float vd = ar.x * adv.x + ar.y * adv.y + ar.z * adv.z + ar.w * adv.w;
#pragma unroll
    for (int m = 1; m < 16; m <<= 1) { vs += __shfl_xor(vs, m); vd += __shfl_xor(vd, m); }
    int gr = rb + r0 + rr;
    if (gr < N_NODES) {
      if (cg == 0) { a_src[h * N_NODES + gr] = vs; a_dst[h * N_NODES + gr] = vd; }
      st_half4(&h1[(size_t)gr * 320 + h * 64 + c0], ar);   // fp16 storage: 128B/head-row
    }
  }
}

// ---- agg1: 8 edge-slots x 8 lanes/edge, 16B fp16 gathers (1 instr = 8 edges) ----

__global__ __launch_bounds__(256) void k_agg1(const __half* __restrict__ h1, const float* __restrict__ a_src,
                                              const float* __restrict__ a_dst, const float* __restrict__ b1,
                                              const int* __restrict__ degs, const int* __restrict__ csr,
                                              float* __restrict__ out1) {
  int lane = threadIdx.x & 63, wid = threadIdx.x >> 6;
  int n = blockIdx.x * 4 + wid;
  int h = blockIdx.y;
  int sub = lane >> 3;        // edge slot 0..7
  int cg = lane & 7;          // channel octet
  int beg = n << 7;
  int deg = degs[n];
  int limit = beg + deg;
  int end = beg + ((deg + 15) & ~15);   // 16-padded iteration space (wave-uniform)
  const float* __restrict__ as = a_src + (size_t)h * N_NODES;
  float adn = a_dst[(size_t)h * N_NODES + n];
  const __half* __restrict__ hh = h1 + h * 64 + cg * 8;
  float4 aclo = make_float4(0.f, 0.f, 0.f, 0.f), achi = aclo;
  float s = 0.f;
  int e = beg + sub;
  bool va = e < limit, vb = e + 8 < limit;
  int t0 = csr[e], t1 = csr[e + 8];
  unsigned i0 = va ? (unsigned)t0 : 0u, i1 = vb ? (unsigned)t1 : 0u;
  float v0 = as[i0], v1 = as[i1];
  for (;;) {
    float4 galo, gahi, gblo, gbhi;
    ld_half8(hh + i0 * 320u, galo, gahi);
    ld_half8(hh + i1 * 320u, gblo, gbhi);
    float pa = va ? lrelu_exp(v0 + adn) : 0.f;
    float pb = vb ? lrelu_exp(v1 + adn) : 0.f;
    e += 16;
    bool more = e < end;                 // wave-uniform
    if (more) {                          // prefetch next slots while gathers in flight
      va = e < limit; vb = e + 8 < limit;
      t0 = csr[e]; t1 = csr[e + 8];
      i0 = va ? (unsigned)t0 : 0u; i1 = vb ? (unsigned)t1 : 0u;
      v0 = as[i0]; v1 = as[i1];
    }
    s += pa + pb;
    aclo.x = fmaf(pb, gblo.x, fmaf(pa, galo.x, aclo.x));
    aclo.y = fmaf(pb, gblo.y, fmaf(pa, galo.y, aclo.y));
    aclo.z = fmaf(pb, gblo.z, fmaf(pa, galo.z, aclo.z));
    aclo.w = fmaf(pb, gblo.w, fmaf(pa, galo.w, aclo.w));
    achi.x = fmaf(pb, gbhi.x, fmaf(pa, gahi.x, achi.x));
    achi.y = fmaf(pb, gbhi.y, fmaf(pa, gahi.y, achi.y));
    achi.z = fmaf(pb, gbhi.z, fmaf(pa, gahi.z, achi.z));
    achi.w = fmaf(pb, gbhi.w, fmaf(pa, gahi.w, achi.w));
    if (!more) break;
  }
#pragma unroll
  for (int m = 8; m <= 32; m <<= 1) {    // reduce across 8 edge-slots
    aclo.x += __shfl_xor(aclo.x, m);
    aclo.y += __shfl_xor(aclo.y, m);
    aclo.z += __shfl_xor(aclo.z, m);
    aclo.w += __shfl_xor(aclo.w, m);
    achi.x += __shfl_xor(achi.x, m);
    achi.y += __shfl_xor(achi.y, m);
    achi.z += __shfl_xor(achi.z, m);
    achi.w += __shfl_xor(achi.w, m);
    s += __shfl_xor(s, m);
  }
  if (sub == 0) {
    float inv = 1.f / (s + 1e-16f);
    const float* bp = b1 + h * 64 + cg * 8;
    float4 b_lo = *reinterpret_cast<const float4*>(bp);
    float4 b_hi = *reinterpret_cast<const float4*>(bp + 4);
    float4 olo, ohi;
    olo.x = fmaxf(fmaf(aclo.x, inv, b_lo.x), 0.f);
    olo.y = fmaxf(fmaf(aclo.y, inv, b_lo.y), 0.f);
    olo.z = fmaxf(fmaf(aclo.z, inv, b_lo.z), 0.f);
    olo.w = fmaxf(fmaf(aclo.w, inv, b_lo.w), 0.f);
    ohi.x = fmaxf(fmaf(achi.x, inv, b_hi.x), 0.f);
    ohi.y = fmaxf(fmaf(achi.y, inv, b_hi.y), 0.f);
    ohi.z = fmaxf(fmaf(achi.z, inv, b_hi.z), 0.f);
    ohi.w = fmaxf(fmaf(achi.w, inv, b_hi.w), 0.f);
    float* op = &out1[(size_t)n * 320 + h * 64 + cg * 8];
    *reinterpret_cast<float4*>(op) = olo;
    *reinterpret_cast<float4*>(op + 4) = ohi;
  }
}

__global__ __launch_bounds__(256) void k_agg2(const __half* __restrict__ h2, const float* __restrict__ a_src,
                                              const float* __restrict__ a_dst, const float* __restrict__ b2,
                                              const int* __restrict__ degs, const int* __restrict__ csr,
                                              float* __restrict__ out) {
  int lane = threadIdx.x & 63, wid = threadIdx.x >> 6;
  int n = blockIdx.x * 4 + wid;
  int sub = lane >> 3;
  int cg = lane & 7;
  int beg = n << 7;
  int deg = degs[n];
  int limit = beg + deg;
  int end = beg + ((deg + 15) & ~15);
  float adn = a_dst[n];
  const __half* __restrict__ hh = h2 + cg * 8;
  float4 aclo = make_float4(0.f, 0.f, 0.f, 0.f), achi = aclo;
  float s = 0.f;
  int e = beg + sub;
  bool va = e < limit, vb = e + 8 < limit;
  int t0 = csr[e], t1 = csr[e + 8];
  unsigned i0 = va ? (unsigned)t0 : 0u, i1 = vb ? (unsigned)t1 : 0u;
  float v0 = a_src[i0], v1 = a_src[i1];
  for (;;) {
    float4 galo, gahi, gblo, gbhi;
    ld_half8(hh + i0 * 64u, galo, gahi);
    ld_half8(hh + i1 * 64u, gblo, gbhi);
    float pa = va ? lrelu_exp(v0 + adn) : 0.f;
    float pb = vb ? lrelu_exp(v1 + adn) : 0.f;
    e += 16;
    bool more = e < end;
    if (more) {
      va = e < limit; vb = e + 8 < limit;
      t0 = csr[e]; t1 = csr[e + 8];
      i0 = va ? (unsigned)t0 : 0u; i1 = vb ? (unsigned)t1 : 0u;
      v0 = a_src[i0]; v1 = a_src[i1];
    }
    s += pa + pb;
    aclo.x = fmaf(pb, gblo.x, fmaf(pa, galo.x, aclo.x));
    aclo.y = fmaf(pb, gblo.y, fmaf(pa, galo.y, aclo.y));
    aclo.z = fmaf(pb, gblo.z, fmaf(pa, galo.z, aclo.z));
    aclo.w = fmaf(pb, gblo.w, fmaf(pa, galo.w, aclo.w));
    achi.x = fmaf(pb, gbhi.x, fmaf(pa, gahi.x, achi.x));
    achi.y = fmaf(pb, gbhi.y, fmaf(pa, gahi.y, achi.y));
    achi.z = fmaf(pb, gbhi.z, fmaf(pa, gahi.z, achi.z));
    achi.w = fmaf(pb, gbhi.w, fmaf(pa, gahi.w, achi.w));
    if (!more) break;
  }
#pragma unroll
  for (int m = 8; m <= 32; m <<= 1) {
    aclo.x += __shfl_xor(aclo.x, m);
    aclo.y += __shfl_xor(aclo.y, m);
    aclo.z += __shfl_xor(aclo.z, m);
    aclo.w += __shfl_xor(aclo.w, m);
    achi.x += __shfl_xor(achi.x, m);
    achi.y += __shfl_xor(achi.y, m);
    achi.z += __shfl_xor(achi.z, m);
    achi.w += __shfl_xor(achi.w, m);
    s += __shfl_xor(s, m);
  }
  if (sub == 0) {
    float inv = 1.f / (s + 1e-16f);
    const float* bp = b2 + cg * 8;
    float4 b_lo = *reinterpret_cast<const float4*>(bp);
    float4 b_hi = *reinterpret_cast<const float4*>(bp + 4);
    float4 olo, ohi;
    olo.x = fmaxf(fmaf(aclo.x, inv, b_lo.x), 0.f);
    olo.y = fmaxf(fmaf(aclo.y, inv, b_lo.y), 0.f);
    olo.z = fmaxf(fmaf(aclo.z, inv, b_lo.z), 0.f);
    olo.w = fmaxf(fmaf(aclo.w, inv, b_lo.w), 0.f);
    ohi.x = fmaxf(fmaf(achi.x, inv, b_hi.x), 0.f);
    ohi.y = fmaxf(fmaf(achi.y, inv, b_hi.y), 0.f);
    ohi.z = fmaxf(fmaf(achi.z, inv, b_hi.z), 0.f);
    ohi.w = fmaxf(fmaf(achi.w, inv, b_hi.w), 0.f);
    float* op = &out[(size_t)n * 64 + cg * 8];
    *reinterpret_cast<float4*>(op) = olo;
    *reinterpret_cast<float4*>(op + 4) = ohi;
  }
}

// ---- layer 2 GEMM: split-K, blockIdx.y = K-chunk (grid 157x5), partials out ----

__global__ __launch_bounds__(256) void k_gemm2(const float* __restrict__ out1, const float* __restrict__ W2,
                                               float* __restrict__ h2part) {
  __shared__ float xs[64][65];
  int t = threadIdx.x;
  int rb = blockIdx.x * 64;
  int kc = blockIdx.y;
#pragma unroll
  for (int i = 0; i < 4; ++i) {
    int idx = t + 256 * i;
    int kq = (idx & 15) * 4;
    int row = idx >> 4;
    int gr = rb + row;
    float4 v = make_float4(0.f, 0.f, 0.f, 0.f);
    if (gr < N_NODES) v = *reinterpret_cast<const float4*>(&out1[(size_t)gr * 320 + kc * 64 + kq]);
    xs[kq + 0][row] = v.x; xs[kq + 1][row] = v.y; xs[kq + 2][row] = v.z; xs[kq + 3][row] = v.w;
  }
  __syncthreads();
  int cg = t & 15, rg = t >> 4;
  int c0 = cg * 4, r0 = rg * 4;
  const float* __restrict__ wp = W2 + (size_t)kc * 64 * 64 + c0;
  float4 a0 = make_float4(0.f,0.f,0.f,0.f), a1 = a0, a2 = a0, a3 = a0;
#pragma unroll 4
  for (int k = 0; k < 64; ++k) {
    float4 xv = *reinterpret_cast<const float4*>(&xs[k][r0]);
    float4 wv = *reinterpret_cast<const float4*>(&wp[(size_t)k * 64]);
    a0.x = fmaf(xv.x, wv.x, a0.x); a0.y = fmaf(xv.x, wv.y, a0.y); a0.z = fmaf(xv.x, wv.z, a0.z); a0.w = fmaf(xv.x, wv.w, a0.w);
    a1.x = fmaf(xv.y, wv.x, a1.x); a1.y = fmaf(xv.y, wv.y, a1.y); a1.z = fmaf(xv.y, wv.z, a1.z); a1.w = fmaf(xv.y, wv.w, a1.w);
    a2.x = fmaf(xv.z, wv.x, a2.x); a2.y = fmaf(xv.z, wv.y, a2.y); a2.z = fmaf(xv.z, wv.z, a2.z); a2.w = fmaf(xv.z, wv.w, a2.w);
    a3.x = fmaf(xv.w, wv.x, a3.x); a3.y = fmaf(xv.w, wv.y, a3.y); a3.z = fmaf(xv.w, wv.z, a3.z); a3.w = fmaf(xv.w, wv.w, a3.w);
  }
  float* __restrict__ hp = h2part + (size_t)kc * N_NODES * 64;
#pragma unroll
  for (int rr = 0; rr < 4; ++rr) {
    float4 ar = (rr == 0) ? a0 : (rr == 1) ? a1 : (rr == 2) ? a2 : a3;
    int gr = rb + r0 + rr;
    if (gr < N_NODES) *reinterpret_cast<float4*>(&hp[(size_t)gr * 64 + c0]) = ar;
  }
}

// ---- reduce 5 partials (fixed order) + att dots; h2 stored fp16 ----

__global__ __launch_bounds__(256) void k_hred2(const float* __restrict__ h2part,
                                               const float* __restrict__ att_src, const float* __restrict__ att_dst,
                                               __half* __restrict__ h2, float* __restrict__ a_src,
                                               float* __restrict__ a_dst) {
  int n = blockIdx.x * 4 + (threadIdx.x >> 6);
  int c = threadIdx.x & 63;
  if (n >= N_NODES) return;
  float v = 0.f;
#pragma unroll
  for (int kc = 0; kc < 5; ++kc) v += h2part[((size_t)kc * N_NODES + n) * 64 + c];
  float vs = v * att_src[c], vd = v * att_dst[c];
  float vnext = __shfl_down(v, 1);
  if ((c & 1) == 0) {
    __half2 p = __float22half2_rn(make_float2(v, vnext));
    *reinterpret_cast<unsigned*>(&h2[(size_t)n * 64 + c]) = *reinterpret_cast<const unsigned*>(&p);
  }
  for (int off = 32; off; off >>= 1) {
    vs += __shfl_down(vs, off);
    vd += __shfl_down(vd, off);
  }
  if (c == 0) { a_src[n] = vs; a_dst[n] = vd; }
}

// ---------------- launch ----------------

extern "C" void kernel_launch(void* const* d_in, const int* in_sizes, int n_in,
                              void* d_out, int out_size, void* d_ws, size_t ws_size,
                              hipStream_t stream) {
  (void)in_sizes; (void)n_in; (void)out_size; (void)ws_size;
  const float* x    = (const float*)d_in[0];
  const int*   ei   = (const int*)d_in[1];
  const float* W1   = (const float*)d_in[2];
  const float* as1w = (const float*)d_in[3];
  const float* ad1w = (const float*)d_in[4];
  const float* b1   = (const float*)d_in[5];
  const float* W2   = (const float*)d_in[6];
  const float* as2w = (const float*)d_in[7];
  const float* ad2w = (const float*)d_in[8];
  const float* b2   = (const float*)d_in[9];
  float* out = (float*)d_out;

  char* ws = (char*)d_ws;
  size_t off = 0;
  auto alloc = [&](size_t bytes) -> void* {
    void* p = ws + off;
    off += (bytes + 255) & ~(size_t)255;
    return p;
  };
  __half* h1     = (__half*)alloc((size_t)N_NODES * 320 * 2);
  float*  out1   = (float*)alloc((size_t)N_NODES * 320 * 4);
  __half* h2     = (__half*)alloc((size_t)N_NODES * 64 * 2);
  float*  h2part = (float*)alloc((size_t)5 * N_NODES * 64 * 4);
  float*  a_src1 = (float*)alloc((size_t)5 * N_NODES * 4);
  float*  a_dst1 = (float*)alloc((size_t)5 * N_NODES * 4);
  float*  a_src2 = (float*)alloc((size_t)N_NODES * 4);
  float*  a_dst2 = (float*)alloc((size_t)N_NODES * 4);
  int*    cursor = (int*)alloc((size_t)N_NODES * 4);
  int*    csr    = (int*)alloc((size_t)N_NODES * CAP * 4);  // pad slots never interpreted: no init

  k_init<<<(N_NODES + 255) / 256, 256, 0, stream>>>(cursor);
  k_gemm1_scatter<<<NB_G1 + NB_SCT, 256, 0, stream>>>(x, W1, as1w, ad1w, h1, a_src1, a_dst1,
                                                      ei, cursor, csr);
  {
    dim3 g(N_NODES / 4, 5);
    k_agg1 <<<g, 256, 0, stream>>>(h1, a_src1, a_dst1, b1, cursor, csr, out1);
  }
  {
    dim3 g((N_NODES + 63) / 64, 5);
    k_gemm2<<<g, 256, 0, stream>>>(out1, W2, h2part);
  }
  k_hred2<<<(N_NODES + 3) / 4, 256, 0, stream>>>(h2part, as2w, ad2w, h2, a_src2, a_dst2);
  k_agg2 <<<N_NODES / 4, 256, 0, stream>>>(h2, a_src2, a_dst2, b2, cursor, csr, out);
}